// Round 10
// baseline (841.394 us; speedup 1.0000x reference)
//
#include <hip/hip_runtime.h>
#include <hip/hip_bf16.h>

#define B_    32
#define T_    256
#define C_    512
#define H_    512
#define TOUT_ 2048
#define TP_   258        // padded time length (zero row at t=0 and t=257)
#define K_    1536       // 3 * 512
#define EPS_  1e-5f

// diagnostic repeat factors (idempotent reps; base time = dur/REP)
#define REP_PREP 8
#define REP_CONV 8
#define REP_LN   16

typedef __attribute__((ext_vector_type(8))) short bf16x8;
typedef __attribute__((ext_vector_type(4))) float f32x4;

#define GLL16(g, l)                                                        \
  __builtin_amdgcn_global_load_lds(                                        \
      (const __attribute__((address_space(1))) void*)(g),                  \
      (__attribute__((address_space(3))) void*)(l), 16, 0, 0)

#define ANTI_LICM asm volatile("" ::: "memory")

// ---------------------------------------------------------------------------
// helpers shared by heterogeneous kernels
// ---------------------------------------------------------------------------
__device__ __forceinline__ void wt_convert_block(const float* __restrict__ W,
                                                 __hip_bfloat16* __restrict__ Wt,
                                                 int k0, int n0, int tid,
                                                 float* tile /* [32][33] */) {
  const int tx = tid & 31;
  const int ty = tid >> 5;
#pragma unroll
  for (int i = 0; i < 4; ++i)
    tile[(ty * 4 + i) * 33 + tx] = W[(size_t)(k0 + ty * 4 + i) * H_ + n0 + tx];
  __syncthreads();
#pragma unroll
  for (int i = 0; i < 4; ++i)
    Wt[(size_t)(n0 + ty * 4 + i) * K_ + k0 + tx] =
        __float2bfloat16(tile[tx * 33 + ty * 4 + i]);
}

// inclusive scan of one batch's 256 durations -> csum
__device__ __forceinline__ void csum_block(const int* __restrict__ dur,
                                           int* __restrict__ csum,
                                           int b, int tid, int* wsum) {
  int v = dur[b * T_ + tid];
#pragma unroll
  for (int off = 1; off < 64; off <<= 1) {
    int u = __shfl_up(v, off);
    if ((tid & 63) >= off) v += u;
  }
  if ((tid & 63) == 63) wsum[tid >> 6] = v;
  __syncthreads();
  int base = 0;
#pragma unroll
  for (int j = 0; j < 4; ++j)
    if (j < (tid >> 6)) base += wsum[j];
  csum[b * T_ + tid] = v + base;
}

// copy block: 16 source rows; read row once, write its d output rows
__device__ __forceinline__ void expand_copy_block(const float* __restrict__ X,
                                                  const int* __restrict__ csum,
                                                  float* __restrict__ res,
                                                  int u, int tid) {
  const int wave = tid >> 6, lane = tid & 63;
#pragma unroll
  for (int k = 0; k < 4; ++k) {
    const int sr = u * 16 + wave * 4 + k;    // 0..8191
    const int b = sr >> 8, t = sr & 255;
    const int* cb = csum + b * T_;
    const int c0 = t ? cb[t - 1] : 0;
    const int d  = cb[t] - c0;
    if (d == 0) continue;
    const float* src = X + (size_t)sr * C_;
    const float4 v0 = *(const float4*)(src + lane * 4);
    const float4 v1 = *(const float4*)(src + 256 + lane * 4);
    float* dst = res + ((size_t)b * TOUT_ + c0) * C_;
    for (int j = 0; j < d; ++j) {
      *(float4*)(dst + (size_t)j * C_ + lane * 4)       = v0;
      *(float4*)(dst + (size_t)j * C_ + 256 + lane * 4) = v1;
    }
  }
}

// zero block: 32 output rows of one batch, zero those >= total
__device__ __forceinline__ void expand_zero_block(const int* __restrict__ csum,
                                                  float* __restrict__ res,
                                                  int z, int tid) {
  const int b  = z >> 6;
  const int t0 = (z & 63) << 5;
  const int total = csum[b * T_ + 255];
  const float4 z4 = make_float4(0.f, 0.f, 0.f, 0.f);
  const int half = tid >> 7, c4 = tid & 127;
#pragma unroll
  for (int rr = half; rr < 32; rr += 2) {
    const int r = t0 + rr;
    if (r >= total)
      *(float4*)(res + ((size_t)b * TOUT_ + r) * C_ + c4 * 4) = z4;
  }
}

// ---------------------------------------------------------------------------
// 1) prep (REP_PREP diagnostic reps)
// ---------------------------------------------------------------------------
__global__ __launch_bounds__(256) void prep_kernel(const float* __restrict__ X,
                                                   const float* __restrict__ W1,
                                                   const int* __restrict__ dur,
                                                   __hip_bfloat16* __restrict__ xpad,
                                                   __hip_bfloat16* __restrict__ hpad,
                                                   __hip_bfloat16* __restrict__ Wt1,
                                                   int* __restrict__ csum) {
  __shared__ float tile[32 * 33];
  const int tid = threadIdx.x;
  for (int rep = 0; rep < REP_PREP; ++rep) {
    ANTI_LICM;
    if (blockIdx.x >= 4896) {
      csum_block(dur, csum, blockIdx.x - 4896, tid, (int*)tile);
    } else if (blockIdx.x >= 4128) {
      const int id = blockIdx.x - 4128;       // 0..767
      wt_convert_block(W1, Wt1, (id % 48) * 32, (id / 48) * 32, tid, tile);
    } else {
      const int row = blockIdx.x * 2 + (tid >> 7);   // 0..8255
      const int b = row / TP_;
      const int t = row - b * TP_;
      const int c = (tid & 127) * 4;
      __hip_bfloat16* dst = xpad + (size_t)row * C_ + c;
      if (t == 0 || t == TP_ - 1) {
        ushort4 zz = make_ushort4(0, 0, 0, 0);
        *(ushort4*)dst = zz;
        *(ushort4*)(hpad + (size_t)row * C_ + c) = zz;
      } else {
        const float4 v = *(const float4*)(X + (size_t)(b * T_ + t - 1) * C_ + c);
        union { __hip_bfloat16 h[4]; ushort4 u; } o;
        o.h[0] = __float2bfloat16(v.x);
        o.h[1] = __float2bfloat16(v.y);
        o.h[2] = __float2bfloat16(v.z);
        o.h[3] = __float2bfloat16(v.w);
        *(ushort4*)dst = o.u;
      }
    }
    __syncthreads();
  }
}

// ---------------------------------------------------------------------------
// 2) heterogeneous: conv GEMM (0..511) || expand units (512..1791)
//    || optional W2 transpose (1792..2559). REP_CONV diagnostic reps.
//    conv: 64x128, BK=32, 3-buf ring, counted vmcnt(6) (R6 structure).
// ---------------------------------------------------------------------------
__global__ __launch_bounds__(256) void conv_expand_kernel(
    const __hip_bfloat16* __restrict__ Apad,   // [32*258, 512]
    const __hip_bfloat16* __restrict__ Wt,     // [512, 1536]
    const float* __restrict__ bias,            // [512]
    float* __restrict__ Y,                     // [8192, 512]
    const float* __restrict__ X,               // f32 input (for expand)
    const int* __restrict__ csum,
    float* __restrict__ res,
    const float* __restrict__ W2,              // may be null
    __hip_bfloat16* __restrict__ Wt2,          // may be null
    int ex_base) {
  __shared__ __hip_bfloat16 smA[3][2048];      // 12 KB
  __shared__ __hip_bfloat16 smB[3][4096];      // 24 KB

  const int tid = threadIdx.x;

  if (blockIdx.x >= 1792) {                    // W2 transpose ride-along
    const int id = blockIdx.x - 1792;          // 0..767
    for (int rep = 0; rep < REP_CONV; ++rep) {
      ANTI_LICM;
      wt_convert_block(W2, Wt2, (id % 48) * 32, (id / 48) * 32, tid, (float*)smA);
      __syncthreads();
    }
    return;
  }
  if (blockIdx.x >= 512) {                     // expand ride-along
    const int u = ex_base + (blockIdx.x - 512);
    for (int rep = 0; rep < REP_CONV; ++rep) {
      ANTI_LICM;
      if (u < 512) expand_copy_block(X, csum, res, u, tid);
      else         expand_zero_block(csum, res, u - 512, tid);
    }
    return;
  }

  // ---- conv GEMM path ----
  const int lane = tid & 63;
  const int wid  = tid >> 6;
  const int cid  = blockIdx.x;
  const int n0 = (cid & 3) << 7;
  const int m0 = (cid >> 2) << 6;
  const int b  = m0 >> 8;
  const int t0 = m0 & 255;
  const int wn = wid << 5;

  const int ra = tid & 63;
  const int ga = tid >> 6;
  const __hip_bfloat16* arow = Apad + (size_t)(b * TP_ + t0 + ra) * C_;
  const int rb = tid & 127;
  const int gb = tid >> 7;
  const __hip_bfloat16* brow = Wt + (size_t)(n0 + rb) * K_;

  for (int rep = 0; rep < REP_CONV; ++rep) {
    ANTI_LICM;
    f32x4 acc[4][2] = {};

    auto stage = [&](int buf, int k0) {
      const int kw = k0 >> 9;
      const int c0 = k0 & 511;
      GLL16(arow + kw * C_ + c0 + (ga << 3), &smA[buf][tid << 3]);
      GLL16(brow + k0 + (gb << 3), &smB[buf][tid << 3]);
      GLL16(brow + k0 + ((gb + 2) << 3), &smB[buf][(tid << 3) + 2048]);
    };

    auto compute = [&](int buf) {
      const __hip_bfloat16* As = smA[buf];
      const __hip_bfloat16* Bs = smB[buf];
      const int g   = lane >> 4;
      const int r15 = lane & 15;
      bf16x8 aF[4], bF[2];
#pragma unroll
      for (int i = 0; i < 4; ++i)
        aF[i] = *(const bf16x8*)(As + (g << 9) + (((i << 4) + r15) << 3));
#pragma unroll
      for (int i = 0; i < 2; ++i)
        bF[i] = *(const bf16x8*)(Bs + (g << 10) + ((wn + (i << 4) + r15) << 3));
#pragma unroll
      for (int mi = 0; mi < 4; ++mi)
#pragma unroll
        for (int ni = 0; ni < 2; ++ni)
          acc[mi][ni] = __builtin_amdgcn_mfma_f32_16x16x32_bf16(
              aF[mi], bF[ni], acc[mi][ni], 0, 0, 0);
    };

    asm volatile("s_waitcnt vmcnt(0)" ::: "memory");
    stage(0, 0);
    stage(1, 32);
    stage(2, 64);

    int buf = 0;
    for (int s = 0; s < 45; ++s) {
      asm volatile("s_waitcnt vmcnt(6)" ::: "memory");
      __builtin_amdgcn_sched_barrier(0);
      __builtin_amdgcn_s_barrier();
      compute(buf);
      asm volatile("s_waitcnt lgkmcnt(0)" ::: "memory");
      __builtin_amdgcn_s_barrier();
      stage(buf, (s + 3) << 5);
      buf = (buf == 2) ? 0 : buf + 1;
    }
    asm volatile("s_waitcnt vmcnt(6)" ::: "memory");
    __builtin_amdgcn_sched_barrier(0);
    __builtin_amdgcn_s_barrier();
    compute(buf);
    buf = (buf == 2) ? 0 : buf + 1;
    asm volatile("s_waitcnt vmcnt(3)" ::: "memory");
    __builtin_amdgcn_sched_barrier(0);
    __builtin_amdgcn_s_barrier();
    compute(buf);
    buf = (buf == 2) ? 0 : buf + 1;
    asm volatile("s_waitcnt vmcnt(0)" ::: "memory");
    __builtin_amdgcn_sched_barrier(0);
    __builtin_amdgcn_s_barrier();
    compute(buf);

    const int cn_base = n0 + wn + (lane & 15);
    const int rm_base = m0 + ((lane >> 4) << 2);
#pragma unroll
    for (int ni = 0; ni < 2; ++ni) {
      const int cn = cn_base + (ni << 4);
      const float bb = bias[cn];
#pragma unroll
      for (int mi = 0; mi < 4; ++mi) {
#pragma unroll
        for (int rq = 0; rq < 4; ++rq) {
          const int rm = rm_base + (mi << 4) + rq;
          Y[(size_t)rm * H_ + cn] = acc[mi][ni][rq] + bb;
        }
      }
    }
    // make LDS safe for next rep's staging
    asm volatile("s_waitcnt vmcnt(0)" ::: "memory");
    __syncthreads();
  }
}

// ---------------------------------------------------------------------------
// 3) LayerNorm + ReLU (REP_LN diagnostic reps)
// ---------------------------------------------------------------------------
__global__ __launch_bounds__(256) void ln_relu_pad_kernel(const float* __restrict__ in,
                                                          const float* __restrict__ g,
                                                          const float* __restrict__ beta,
                                                          __hip_bfloat16* __restrict__ outpad) {
  const int wave = threadIdx.x >> 6;
  const int lane = threadIdx.x & 63;
  const int row  = blockIdx.x * 4 + wave;   // 0..8191
  const float* r = in + (size_t)row * H_;

  for (int rep = 0; rep < REP_LN; ++rep) {
    ANTI_LICM;
    const float4 v0 = *(const float4*)(r + lane * 4);
    const float4 v1 = *(const float4*)(r + 256 + lane * 4);

    float s = v0.x + v0.y + v0.z + v0.w + v1.x + v1.y + v1.z + v1.w;
    float q = v0.x * v0.x + v0.y * v0.y + v0.z * v0.z + v0.w * v0.w +
              v1.x * v1.x + v1.y * v1.y + v1.z * v1.z + v1.w * v1.w;
#pragma unroll
    for (int off = 32; off; off >>= 1) {
      s += __shfl_xor(s, off);
      q += __shfl_xor(q, off);
    }
    const float mu  = s * (1.0f / 512.0f);
    const float var = q * (1.0f / 512.0f) - mu * mu;
    const float rs  = rsqrtf(var + EPS_);

    const float4 g0 = *(const float4*)(g + lane * 4);
    const float4 g1 = *(const float4*)(g + 256 + lane * 4);
    const float4 e0 = *(const float4*)(beta + lane * 4);
    const float4 e1 = *(const float4*)(beta + 256 + lane * 4);

    union { __hip_bfloat16 h[4]; ushort4 u; } o0, o1;
    o0.h[0] = __float2bfloat16(fmaxf(0.f, (v0.x - mu) * rs * g0.x + e0.x));
    o0.h[1] = __float2bfloat16(fmaxf(0.f, (v0.y - mu) * rs * g0.y + e0.y));
    o0.h[2] = __float2bfloat16(fmaxf(0.f, (v0.z - mu) * rs * g0.z + e0.z));
    o0.h[3] = __float2bfloat16(fmaxf(0.f, (v0.w - mu) * rs * g0.w + e0.w));
    o1.h[0] = __float2bfloat16(fmaxf(0.f, (v1.x - mu) * rs * g1.x + e1.x));
    o1.h[1] = __float2bfloat16(fmaxf(0.f, (v1.y - mu) * rs * g1.y + e1.y));
    o1.h[2] = __float2bfloat16(fmaxf(0.f, (v1.z - mu) * rs * g1.z + e1.z));
    o1.h[3] = __float2bfloat16(fmaxf(0.f, (v1.w - mu) * rs * g1.w + e1.w));

    const int bq = row >> 8, t = row & 255;
    __hip_bfloat16* w = outpad + (size_t)(bq * TP_ + t + 1) * H_;
    *(ushort4*)(w + lane * 4)       = o0.u;
    *(ushort4*)(w + 256 + lane * 4) = o1.u;
  }
}

// ---------------------------------------------------------------------------
// 4) LayerNorm + ReLU + linear head fused (REP_LN diagnostic reps)
// ---------------------------------------------------------------------------
__global__ __launch_bounds__(256) void ln_relu_linear_kernel(const float* __restrict__ in,
                                                             const float* __restrict__ g,
                                                             const float* __restrict__ beta,
                                                             const float* __restrict__ Wl,
                                                             const float* __restrict__ bl,
                                                             float* __restrict__ out) {
  const int wave = threadIdx.x >> 6;
  const int lane = threadIdx.x & 63;
  const int row  = blockIdx.x * 4 + wave;
  const float* r = in + (size_t)row * H_;

  for (int rep = 0; rep < REP_LN; ++rep) {
    ANTI_LICM;
    const float4 v0 = *(const float4*)(r + lane * 4);
    const float4 v1 = *(const float4*)(r + 256 + lane * 4);

    float s = v0.x + v0.y + v0.z + v0.w + v1.x + v1.y + v1.z + v1.w;
    float q = v0.x * v0.x + v0.y * v0.y + v0.z * v0.z + v0.w * v0.w +
              v1.x * v1.x + v1.y * v1.y + v1.z * v1.z + v1.w * v1.w;
#pragma unroll
    for (int off = 32; off; off >>= 1) {
      s += __shfl_xor(s, off);
      q += __shfl_xor(q, off);
    }
    const float mu  = s * (1.0f / 512.0f);
    const float var = q * (1.0f / 512.0f) - mu * mu;
    const float rs  = rsqrtf(var + EPS_);

    const float4 g0 = *(const float4*)(g + lane * 4);
    const float4 g1 = *(const float4*)(g + 256 + lane * 4);
    const float4 e0 = *(const float4*)(beta + lane * 4);
    const float4 e1 = *(const float4*)(beta + 256 + lane * 4);
    const float4 w0 = *(const float4*)(Wl + lane * 4);
    const float4 w1 = *(const float4*)(Wl + 256 + lane * 4);

    float sd = 0.f;
    sd += fmaxf(0.f, (v0.x - mu) * rs * g0.x + e0.x) * w0.x;
    sd += fmaxf(0.f, (v0.y - mu) * rs * g0.y + e0.y) * w0.y;
    sd += fmaxf(0.f, (v0.z - mu) * rs * g0.z + e0.z) * w0.z;
    sd += fmaxf(0.f, (v0.w - mu) * rs * g0.w + e0.w) * w0.w;
    sd += fmaxf(0.f, (v1.x - mu) * rs * g1.x + e1.x) * w1.x;
    sd += fmaxf(0.f, (v1.y - mu) * rs * g1.y + e1.y) * w1.y;
    sd += fmaxf(0.f, (v1.z - mu) * rs * g1.z + e1.z) * w1.z;
    sd += fmaxf(0.f, (v1.w - mu) * rs * g1.w + e1.w) * w1.w;
#pragma unroll
    for (int off = 32; off; off >>= 1) sd += __shfl_xor(sd, off);

    if (lane == 0) out[row] = sd + bl[0];
  }
}

// ---------------------------------------------------------------------------
extern "C" void kernel_launch(void* const* d_in, const int* in_sizes, int n_in,
                              void* d_out, int out_size, void* d_ws, size_t ws_size,
                              hipStream_t stream) {
  const float* x     = (const float*)d_in[0];
  const int*   dur   = (const int*)d_in[1];
  const float* W1    = (const float*)d_in[2];
  const float* b1    = (const float*)d_in[3];
  const float* g1    = (const float*)d_in[4];
  const float* beta1 = (const float*)d_in[5];
  const float* W2    = (const float*)d_in[6];
  const float* b2    = (const float*)d_in[7];
  const float* g2    = (const float*)d_in[8];
  const float* beta2 = (const float*)d_in[9];
  const float* Wl    = (const float*)d_in[10];
  const float* bl    = (const float*)d_in[11];

  float* out = (float*)d_out;
  float* res    = out;                              // [B, TOUT, C]
  float* loglen = out + (size_t)B_ * TOUT_ * C_;    // [B, T]

  char* ws = (char*)d_ws;
  __hip_bfloat16* xpad = (__hip_bfloat16*)ws;                       // 8.45 MB
  __hip_bfloat16* hpad = xpad + (size_t)B_ * TP_ * C_;              // 8.45 MB
  __hip_bfloat16* Wt1  = hpad + (size_t)B_ * TP_ * C_;              // 1.57 MB
  __hip_bfloat16* Wt2  = Wt1 + (size_t)H_ * K_;                     // 1.57 MB
  float* tmp1 = (float*)(Wt2 + (size_t)H_ * K_);                    // 16.8 MB
  int*   csum = (int*)(tmp1 + (size_t)B_ * T_ * H_);                // 32 KB

  prep_kernel<<<4928, 256, 0, stream>>>(x, W1, dur, xpad, hpad, Wt1, csum);

  // conv1 || expand units 0..1279 (all copies + zeros 0..767) || W2 transpose
  conv_expand_kernel<<<2560, 256, 0, stream>>>(xpad, Wt1, b1, tmp1,
                                               x, csum, res, W2, Wt2, 0);
  ln_relu_pad_kernel<<<B_ * T_ / 4, 256, 0, stream>>>(tmp1, g1, beta1, hpad);

  // conv2 || expand units 1280..2559 (zeros 768..2047)
  conv_expand_kernel<<<1792, 256, 0, stream>>>(hpad, Wt2, b2, tmp1,
                                               x, csum, res, nullptr, nullptr, 1280);
  ln_relu_linear_kernel<<<B_ * T_ / 4, 256, 0, stream>>>(tmp1, g2, beta2, Wl, bl, loglen);
}

// Round 11
// 137.478 us; speedup vs baseline: 6.1202x; 6.1202x over previous
//
#include <hip/hip_runtime.h>
#include <hip/hip_bf16.h>

#define B_    32
#define T_    256
#define C_    512
#define H_    512
#define TOUT_ 2048
#define TP_   258        // padded time length (zero row at t=0 and t=257)
#define K_    1536       // 3 * 512
#define EPS_  1e-5f

typedef __attribute__((ext_vector_type(8))) short bf16x8;
typedef __attribute__((ext_vector_type(4))) float f32x4;

#define GLL16(g, l)                                                        \
  __builtin_amdgcn_global_load_lds(                                        \
      (const __attribute__((address_space(1))) void*)(g),                  \
      (__attribute__((address_space(3))) void*)(l), 16, 0, 0)

// ---------------------------------------------------------------------------
// helpers shared by heterogeneous kernels
// ---------------------------------------------------------------------------
__device__ __forceinline__ void wt_convert_block(const float* __restrict__ W,
                                                 __hip_bfloat16* __restrict__ Wt,
                                                 int k0, int n0, int tid,
                                                 float* tile /* [32][33] */) {
  const int tx = tid & 31;
  const int ty = tid >> 5;
#pragma unroll
  for (int i = 0; i < 4; ++i)
    tile[(ty * 4 + i) * 33 + tx] = W[(size_t)(k0 + ty * 4 + i) * H_ + n0 + tx];
  __syncthreads();
#pragma unroll
  for (int i = 0; i < 4; ++i)
    Wt[(size_t)(n0 + ty * 4 + i) * K_ + k0 + tx] =
        __float2bfloat16(tile[tx * 33 + ty * 4 + i]);
}

// inclusive scan of one batch's 256 durations -> csum
__device__ __forceinline__ void csum_block(const int* __restrict__ dur,
                                           int* __restrict__ csum,
                                           int b, int tid, int* wsum) {
  int v = dur[b * T_ + tid];
#pragma unroll
  for (int off = 1; off < 64; off <<= 1) {
    int u = __shfl_up(v, off);
    if ((tid & 63) >= off) v += u;
  }
  if ((tid & 63) == 63) wsum[tid >> 6] = v;
  __syncthreads();
  int base = 0;
#pragma unroll
  for (int j = 0; j < 4; ++j)
    if (j < (tid >> 6)) base += wsum[j];
  csum[b * T_ + tid] = v + base;
}

// copy block: 16 source rows; read row once, write its d output rows
__device__ __forceinline__ void expand_copy_block(const float* __restrict__ X,
                                                  const int* __restrict__ csum,
                                                  float* __restrict__ res,
                                                  int u, int tid) {
  const int wave = tid >> 6, lane = tid & 63;
#pragma unroll
  for (int k = 0; k < 4; ++k) {
    const int sr = u * 16 + wave * 4 + k;    // 0..8191
    const int b = sr >> 8, t = sr & 255;
    const int* cb = csum + b * T_;
    const int c0 = t ? cb[t - 1] : 0;
    const int d  = cb[t] - c0;
    if (d == 0) continue;
    const float* src = X + (size_t)sr * C_;
    const float4 v0 = *(const float4*)(src + lane * 4);
    const float4 v1 = *(const float4*)(src + 256 + lane * 4);
    float* dst = res + ((size_t)b * TOUT_ + c0) * C_;
    for (int j = 0; j < d; ++j) {
      *(float4*)(dst + (size_t)j * C_ + lane * 4)       = v0;
      *(float4*)(dst + (size_t)j * C_ + 256 + lane * 4) = v1;
    }
  }
}

// zero block: 32 output rows of one batch, zero those >= total
__device__ __forceinline__ void expand_zero_block(const int* __restrict__ csum,
                                                  float* __restrict__ res,
                                                  int z, int tid) {
  const int b  = z >> 6;
  const int t0 = (z & 63) << 5;
  const int total = csum[b * T_ + 255];
  const float4 z4 = make_float4(0.f, 0.f, 0.f, 0.f);
  const int half = tid >> 7, c4 = tid & 127;
#pragma unroll
  for (int rr = half; rr < 32; rr += 2) {
    const int r = t0 + rr;
    if (r >= total)
      *(float4*)(res + ((size_t)b * TOUT_ + r) * C_ + c4 * 4) = z4;
  }
}

// ---------------------------------------------------------------------------
// 1) prep: cvt_x_pad (0..4127) + cvt W1 (4128..4895) + csum (4896..4927)
// ---------------------------------------------------------------------------
__global__ __launch_bounds__(256) void prep_kernel(const float* __restrict__ X,
                                                   const float* __restrict__ W1,
                                                   const int* __restrict__ dur,
                                                   __hip_bfloat16* __restrict__ xpad,
                                                   __hip_bfloat16* __restrict__ hpad,
                                                   __hip_bfloat16* __restrict__ Wt1,
                                                   int* __restrict__ csum) {
  __shared__ float tile[32 * 33];
  const int tid = threadIdx.x;
  if (blockIdx.x >= 4896) {
    csum_block(dur, csum, blockIdx.x - 4896, tid, (int*)tile);
    return;
  }
  if (blockIdx.x >= 4128) {
    const int id = blockIdx.x - 4128;       // 0..767
    wt_convert_block(W1, Wt1, (id % 48) * 32, (id / 48) * 32, tid, tile);
    return;
  }
  const int row = blockIdx.x * 2 + (tid >> 7);   // 0..8255
  const int b = row / TP_;
  const int t = row - b * TP_;
  const int c = (tid & 127) * 4;
  __hip_bfloat16* dst = xpad + (size_t)row * C_ + c;
  if (t == 0 || t == TP_ - 1) {
    ushort4 zz = make_ushort4(0, 0, 0, 0);
    *(ushort4*)dst = zz;
    *(ushort4*)(hpad + (size_t)row * C_ + c) = zz;
    return;
  }
  const float4 v = *(const float4*)(X + (size_t)(b * T_ + t - 1) * C_ + c);
  union { __hip_bfloat16 h[4]; ushort4 u; } o;
  o.h[0] = __float2bfloat16(v.x);
  o.h[1] = __float2bfloat16(v.y);
  o.h[2] = __float2bfloat16(v.z);
  o.h[3] = __float2bfloat16(v.w);
  *(ushort4*)dst = o.u;
}

// ---------------------------------------------------------------------------
// 2) heterogeneous: conv GEMM (0..1023) || expand units (1024..2303)
//    || optional W2 transpose (2304..3071, first dispatch only)
//    conv: 64x64 tile, BK=32, 4 waves (2x2 of 32x32), 16 KB LDS dbuf,
//    simple 2-phase loop — high occupancy (~8 blocks/CU) does the hiding.
// ---------------------------------------------------------------------------
__global__ __launch_bounds__(256) void conv_expand_kernel(
    const __hip_bfloat16* __restrict__ Apad,   // [32*258, 512]
    const __hip_bfloat16* __restrict__ Wt,     // [512, 1536]
    const float* __restrict__ bias,            // [512]
    float* __restrict__ Y,                     // [8192, 512]
    const float* __restrict__ X,               // f32 input (for expand)
    const int* __restrict__ csum,
    float* __restrict__ res,
    const float* __restrict__ W2,              // may be null
    __hip_bfloat16* __restrict__ Wt2,          // may be null
    int ex_base) {
  __shared__ __hip_bfloat16 smA[2][2048];      // 8 KB
  __shared__ __hip_bfloat16 smB[2][2048];      // 8 KB

  const int tid = threadIdx.x;

  if (blockIdx.x >= 2304) {                    // W2 transpose ride-along
    const int id = blockIdx.x - 2304;          // 0..767
    wt_convert_block(W2, Wt2, (id % 48) * 32, (id / 48) * 32, tid, (float*)smA);
    return;
  }
  if (blockIdx.x >= 1024) {                    // expand ride-along
    const int u = ex_base + (blockIdx.x - 1024);
    if (u < 512) expand_copy_block(X, csum, res, u, tid);
    else         expand_zero_block(csum, res, u - 512, tid);
    return;
  }

  // ---- conv GEMM path: 64(M) x 64(N) ----
  const int lane = tid & 63;
  const int wid  = tid >> 6;
  const int cid  = blockIdx.x;
  const int n0 = (cid & 7) << 6;
  const int m0 = (cid >> 3) << 6;
  const int b  = m0 >> 8;
  const int t0 = m0 & 255;
  const int wm = (wid >> 1) << 5;              // 0 / 32
  const int wn = (wid & 1) << 5;               // 0 / 32

  // staging: thread -> row ra (0..63), k-slab ga (0..3); 1 GLL16 for A, 1 for B
  const int ra = tid & 63;
  const int ga = tid >> 6;
  const __hip_bfloat16* arow = Apad + (size_t)(b * TP_ + t0 + ra) * C_;
  const __hip_bfloat16* brow = Wt + (size_t)(n0 + ra) * K_;

  f32x4 acc[2][2] = {};

  auto stage = [&](int buf, int k0) {
    const int kw = k0 >> 9;                    // 0..2 (BK=32 never straddles)
    const int c0 = k0 & 511;
    GLL16(arow + kw * C_ + c0 + (ga << 3), &smA[buf][tid << 3]);
    GLL16(brow + k0 + (ga << 3), &smB[buf][tid << 3]);
  };

  auto compute = [&](int buf) {
    const __hip_bfloat16* As = smA[buf];
    const __hip_bfloat16* Bs = smB[buf];
    const int g   = lane >> 4;
    const int r15 = lane & 15;
    bf16x8 aF[2], bF[2];
#pragma unroll
    for (int i = 0; i < 2; ++i) {
      aF[i] = *(const bf16x8*)(As + (g << 9) + ((wm + (i << 4) + r15) << 3));
      bF[i] = *(const bf16x8*)(Bs + (g << 9) + ((wn + (i << 4) + r15) << 3));
    }
#pragma unroll
    for (int mi = 0; mi < 2; ++mi)
#pragma unroll
      for (int ni = 0; ni < 2; ++ni)
        acc[mi][ni] = __builtin_amdgcn_mfma_f32_16x16x32_bf16(
            aF[mi], bF[ni], acc[mi][ni], 0, 0, 0);
  };

  stage(0, 0);
  __syncthreads();
  int cur = 0;
  for (int k0 = 32; k0 < K_; k0 += 32) {
    stage(cur ^ 1, k0);
    compute(cur);
    __syncthreads();
    cur ^= 1;
  }
  compute(cur);

  // epilogue: C/D layout col = lane&15 (n), row = (lane>>4)*4 + reg (m)
  const int cn_base = n0 + wn + (lane & 15);
  const int rm_base = m0 + wm + ((lane >> 4) << 2);
#pragma unroll
  for (int ni = 0; ni < 2; ++ni) {
    const int cn = cn_base + (ni << 4);
    const float bb = bias[cn];
#pragma unroll
    for (int mi = 0; mi < 2; ++mi) {
#pragma unroll
      for (int rq = 0; rq < 4; ++rq) {
        const int rm = rm_base + (mi << 4) + rq;
        Y[(size_t)rm * H_ + cn] = acc[mi][ni][rq] + bb;
      }
    }
  }
}

// ---------------------------------------------------------------------------
// 3) LayerNorm + ReLU, f32 in -> bf16 out written into padded layout
// ---------------------------------------------------------------------------
__global__ __launch_bounds__(256) void ln_relu_pad_kernel(const float* __restrict__ in,
                                                          const float* __restrict__ g,
                                                          const float* __restrict__ beta,
                                                          __hip_bfloat16* __restrict__ outpad) {
  const int wave = threadIdx.x >> 6;
  const int lane = threadIdx.x & 63;
  const int row  = blockIdx.x * 4 + wave;   // 0..8191
  const float* r = in + (size_t)row * H_;

  const float4 v0 = *(const float4*)(r + lane * 4);
  const float4 v1 = *(const float4*)(r + 256 + lane * 4);

  float s = v0.x + v0.y + v0.z + v0.w + v1.x + v1.y + v1.z + v1.w;
  float q = v0.x * v0.x + v0.y * v0.y + v0.z * v0.z + v0.w * v0.w +
            v1.x * v1.x + v1.y * v1.y + v1.z * v1.z + v1.w * v1.w;
#pragma unroll
  for (int off = 32; off; off >>= 1) {
    s += __shfl_xor(s, off);
    q += __shfl_xor(q, off);
  }
  const float mu  = s * (1.0f / 512.0f);
  const float var = q * (1.0f / 512.0f) - mu * mu;
  const float rs  = rsqrtf(var + EPS_);

  const float4 g0 = *(const float4*)(g + lane * 4);
  const float4 g1 = *(const float4*)(g + 256 + lane * 4);
  const float4 e0 = *(const float4*)(beta + lane * 4);
  const float4 e1 = *(const float4*)(beta + 256 + lane * 4);

  union { __hip_bfloat16 h[4]; ushort4 u; } o0, o1;
  o0.h[0] = __float2bfloat16(fmaxf(0.f, (v0.x - mu) * rs * g0.x + e0.x));
  o0.h[1] = __float2bfloat16(fmaxf(0.f, (v0.y - mu) * rs * g0.y + e0.y));
  o0.h[2] = __float2bfloat16(fmaxf(0.f, (v0.z - mu) * rs * g0.z + e0.z));
  o0.h[3] = __float2bfloat16(fmaxf(0.f, (v0.w - mu) * rs * g0.w + e0.w));
  o1.h[0] = __float2bfloat16(fmaxf(0.f, (v1.x - mu) * rs * g1.x + e1.x));
  o1.h[1] = __float2bfloat16(fmaxf(0.f, (v1.y - mu) * rs * g1.y + e1.y));
  o1.h[2] = __float2bfloat16(fmaxf(0.f, (v1.z - mu) * rs * g1.z + e1.z));
  o1.h[3] = __float2bfloat16(fmaxf(0.f, (v1.w - mu) * rs * g1.w + e1.w));

  const int bq = row >> 8, t = row & 255;
  __hip_bfloat16* w = outpad + (size_t)(bq * TP_ + t + 1) * H_;
  *(ushort4*)(w + lane * 4)       = o0.u;
  *(ushort4*)(w + 256 + lane * 4) = o1.u;
}

// ---------------------------------------------------------------------------
// 4) LayerNorm + ReLU + linear head fused
// ---------------------------------------------------------------------------
__global__ __launch_bounds__(256) void ln_relu_linear_kernel(const float* __restrict__ in,
                                                             const float* __restrict__ g,
                                                             const float* __restrict__ beta,
                                                             const float* __restrict__ Wl,
                                                             const float* __restrict__ bl,
                                                             float* __restrict__ out) {
  const int wave = threadIdx.x >> 6;
  const int lane = threadIdx.x & 63;
  const int row  = blockIdx.x * 4 + wave;
  const float* r = in + (size_t)row * H_;

  const float4 v0 = *(const float4*)(r + lane * 4);
  const float4 v1 = *(const float4*)(r + 256 + lane * 4);

  float s = v0.x + v0.y + v0.z + v0.w + v1.x + v1.y + v1.z + v1.w;
  float q = v0.x * v0.x + v0.y * v0.y + v0.z * v0.z + v0.w * v0.w +
            v1.x * v1.x + v1.y * v1.y + v1.z * v1.z + v1.w * v1.w;
#pragma unroll
  for (int off = 32; off; off >>= 1) {
    s += __shfl_xor(s, off);
    q += __shfl_xor(q, off);
  }
  const float mu  = s * (1.0f / 512.0f);
  const float var = q * (1.0f / 512.0f) - mu * mu;
  const float rs  = rsqrtf(var + EPS_);

  const float4 g0 = *(const float4*)(g + lane * 4);
  const float4 g1 = *(const float4*)(g + 256 + lane * 4);
  const float4 e0 = *(const float4*)(beta + lane * 4);
  const float4 e1 = *(const float4*)(beta + 256 + lane * 4);
  const float4 w0 = *(const float4*)(Wl + lane * 4);
  const float4 w1 = *(const float4*)(Wl + 256 + lane * 4);

  float sd = 0.f;
  sd += fmaxf(0.f, (v0.x - mu) * rs * g0.x + e0.x) * w0.x;
  sd += fmaxf(0.f, (v0.y - mu) * rs * g0.y + e0.y) * w0.y;
  sd += fmaxf(0.f, (v0.z - mu) * rs * g0.z + e0.z) * w0.z;
  sd += fmaxf(0.f, (v0.w - mu) * rs * g0.w + e0.w) * w0.w;
  sd += fmaxf(0.f, (v1.x - mu) * rs * g1.x + e1.x) * w1.x;
  sd += fmaxf(0.f, (v1.y - mu) * rs * g1.y + e1.y) * w1.y;
  sd += fmaxf(0.f, (v1.z - mu) * rs * g1.z + e1.z) * w1.z;
  sd += fmaxf(0.f, (v1.w - mu) * rs * g1.w + e1.w) * w1.w;
#pragma unroll
  for (int off = 32; off; off >>= 1) sd += __shfl_xor(sd, off);

  if (lane == 0) out[row] = sd + bl[0];
}

// ---------------------------------------------------------------------------
extern "C" void kernel_launch(void* const* d_in, const int* in_sizes, int n_in,
                              void* d_out, int out_size, void* d_ws, size_t ws_size,
                              hipStream_t stream) {
  const float* x     = (const float*)d_in[0];
  const int*   dur   = (const int*)d_in[1];
  const float* W1    = (const float*)d_in[2];
  const float* b1    = (const float*)d_in[3];
  const float* g1    = (const float*)d_in[4];
  const float* beta1 = (const float*)d_in[5];
  const float* W2    = (const float*)d_in[6];
  const float* b2    = (const float*)d_in[7];
  const float* g2    = (const float*)d_in[8];
  const float* beta2 = (const float*)d_in[9];
  const float* Wl    = (const float*)d_in[10];
  const float* bl    = (const float*)d_in[11];

  float* out = (float*)d_out;
  float* res    = out;                              // [B, TOUT, C]
  float* loglen = out + (size_t)B_ * TOUT_ * C_;    // [B, T]

  char* ws = (char*)d_ws;
  __hip_bfloat16* xpad = (__hip_bfloat16*)ws;                       // 8.45 MB
  __hip_bfloat16* hpad = xpad + (size_t)B_ * TP_ * C_;              // 8.45 MB
  __hip_bfloat16* Wt1  = hpad + (size_t)B_ * TP_ * C_;              // 1.57 MB
  __hip_bfloat16* Wt2  = Wt1 + (size_t)H_ * K_;                     // 1.57 MB
  float* tmp1 = (float*)(Wt2 + (size_t)H_ * K_);                    // 16.8 MB
  int*   csum = (int*)(tmp1 + (size_t)B_ * T_ * H_);                // 32 KB

  prep_kernel<<<4928, 256, 0, stream>>>(x, W1, dur, xpad, hpad, Wt1, csum);

  // conv1 (1024) || expand units 0..1279 || W2 transpose (768)
  conv_expand_kernel<<<3072, 256, 0, stream>>>(xpad, Wt1, b1, tmp1,
                                               x, csum, res, W2, Wt2, 0);
  ln_relu_pad_kernel<<<B_ * T_ / 4, 256, 0, stream>>>(tmp1, g1, beta1, hpad);

  // conv2 (1024) || expand units 1280..2559 (zeros 768..2047)
  conv_expand_kernel<<<2304, 256, 0, stream>>>(hpad, Wt2, b2, tmp1,
                                               x, csum, res, nullptr, nullptr, 1280);
  ln_relu_linear_kernel<<<B_ * T_ / 4, 256, 0, stream>>>(tmp1, g2, beta2, Wl, bl, loglen);
}